// Round 1
// 315.297 us; speedup vs baseline: 1.0068x; 1.0068x over previous
//
#include <hip/hip_runtime.h>
#include <hip/hip_bf16.h>
#include <math.h>

// Problem constants
constexpr int Bn  = 4;
constexpr int Ln  = 1024;
constexpr int Dn  = 768;
constexpr int Hn  = 12;
constexpr int NEn = 42;
constexpr int Mn  = 8;
constexpr int Pn  = NEn * (NEn - 1);   // 1722
constexpr int OFFn = 1;
constexpr float EPSn = 1e-5f;
constexpr int CL = 32;                 // l-chunk for k_pairs
constexpr int CHUNKS = Ln / CL;        // 32
constexpr int HALFP = Pn / 2;          // 861

constexpr int SOT_BLKS = (Ln / 32) * (Dn / 32) * Bn;   // 3072
constexpr int EA_BLKS  = Bn * Hn * NEn;                // 2016

typedef __attribute__((ext_vector_type(8))) short bf16x8;
typedef __attribute__((ext_vector_type(4))) float f32x4;

__device__ inline unsigned short f2bf(float v) {  // RNE fp32 -> bf16 bits
    unsigned u = __float_as_uint(v);
    u += 0x7fffu + ((u >> 16) & 1u);
    return (unsigned short)(u >> 16);
}

// async global->LDS 16B DMA. LDS dest is wave-uniform base + lane*16 (HW rule),
// so the per-lane GLOBAL address carries any swizzle (guide rule #21).
__device__ inline void gld16(const unsigned short* g, unsigned short* l) {
    typedef __attribute__((address_space(3))) unsigned lds_u32;
    typedef const __attribute__((address_space(1))) unsigned glb_u32;
    __builtin_amdgcn_global_load_lds((glb_u32*)g, (lds_u32*)(uintptr_t)l, 16, 0, 0);
}

// ---------------------------------------------------------------------------
// K1: entity_embed (fp32). Launched LAST (round-4 passing configuration).
// ---------------------------------------------------------------------------
__global__ __launch_bounds__(256) void k_entity_embed(
    const float* __restrict__ so, const float* __restrict__ mask,
    const int* __restrict__ mpos, float* __restrict__ out)
{
    const int be = blockIdx.x;
    const int b = be / NEn, e = be % NEn;
    __shared__ int   s_idx[Mn];
    __shared__ float s_msk[Mn];
    if (threadIdx.x < Mn) {
        const int m = threadIdx.x;
        s_idx[m] = mpos[(b * NEn + e) * Mn + m] + OFFn;
        s_msk[m] = mask[(b * NEn + e) * Mn + m];
    }
    __syncthreads();
    for (int d = threadIdx.x; d < Dn; d += 256) {
        float v[Mn];
        float mx = -3.4e38f;
        #pragma unroll
        for (int m = 0; m < Mn; ++m) {
            const float val = so[((size_t)b * Ln + s_idx[m]) * Dn + d];
            v[m] = (s_msk[m] > 0.f) ? val : -3.4e38f;
            mx = fmaxf(mx, v[m]);
        }
        float s = 0.f;
        #pragma unroll
        for (int m = 0; m < Mn; ++m)
            s += (v[m] > -3.0e38f) ? __expf(v[m] - mx) : 0.f;
        out[((size_t)b * NEn + e) * Dn + d] = mx + __logf(s);
    }
}

// ---------------------------------------------------------------------------
// K_prep: fused  [blocks 0..SOT_BLKS)  : so -> soT (bf16, transposed)
//                [SOT_BLKS..+EA_BLKS)  : entity_att -> ea2 (bf16)
// ---------------------------------------------------------------------------
__global__ __launch_bounds__(256) void k_prep(
    const float* __restrict__ so, const float* __restrict__ att,
    const float* __restrict__ mask, const int* __restrict__ mpos,
    unsigned short* __restrict__ soT, unsigned short* __restrict__ ea2)
{
    const int bx = blockIdx.x;
    if (bx < SOT_BLKS) {
        __shared__ unsigned short tile[32][33];
        const int rem = bx % ((Ln / 32) * (Dn / 32));
        const int b   = bx / ((Ln / 32) * (Dn / 32));
        const int l0  = (rem % (Ln / 32)) * 32;
        const int d0  = (rem / (Ln / 32)) * 32;
        const int cx = threadIdx.x & 31;
        const int ry = threadIdx.x >> 5;  // 0..7
        for (int r = ry; r < 32; r += 8)
            tile[r][cx] = f2bf(so[((size_t)b * Ln + l0 + r) * Dn + d0 + cx]);
        __syncthreads();
        for (int r = ry; r < 32; r += 8)
            soT[((size_t)b * Dn + d0 + r) * Ln + l0 + cx] = tile[cx][r];
    } else {
        const int id = bx - SOT_BLKS;     // ((b*H)+h)*NE + e
        const int e = id % NEn;
        const int bh = id / NEn;
        const int h = bh % Hn;
        const int b = bh / Hn;
        __shared__ int   s_idx[Mn];
        __shared__ float s_w[Mn];
        __shared__ float s_inv;
        if (threadIdx.x == 0) {
            float sum = 0.f;
            for (int m = 0; m < Mn; ++m) {
                s_idx[m] = mpos[(b * NEn + e) * Mn + m] + OFFn;
                const float w = mask[(b * NEn + e) * Mn + m];
                s_w[m] = w; sum += w;
            }
            s_inv = 1.f / sum;
        }
        __syncthreads();
        const int l = threadIdx.x * 4;
        float4 acc = {0.f, 0.f, 0.f, 0.f};
        #pragma unroll
        for (int m = 0; m < Mn; ++m) {
            if (s_w[m] > 0.f) {
                const float4 v = *(const float4*)&att[(((size_t)b * Hn + h) * Ln + s_idx[m]) * Ln + l];
                acc.x += v.x; acc.y += v.y; acc.z += v.z; acc.w += v.w;
            }
        }
        const unsigned u0 = (unsigned)f2bf(acc.x * s_inv) | ((unsigned)f2bf(acc.y * s_inv) << 16);
        const unsigned u1 = (unsigned)f2bf(acc.z * s_inv) | ((unsigned)f2bf(acc.w * s_inv) << 16);
        uint2 uu; uu.x = u0; uu.y = u1;
        *(uint2*)&ea2[((size_t)id) * Ln + l] = uu;
    }
}

// ---------------------------------------------------------------------------
// K3a: pair scores, unnormalized, PAIR-RANK order. Unchanged.
// ---------------------------------------------------------------------------
__global__ __launch_bounds__(256) void k_pairs(
    const unsigned short* __restrict__ ea2, unsigned short* __restrict__ xb,
    float* __restrict__ Spart)
{
    __shared__ unsigned sm[Hn * NEn * 17];   // [h*NE+e][16 uints + 1 pad]
    const int c    = blockIdx.x;
    const int half = blockIdx.y;
    const int b    = blockIdx.z;
    const int t    = threadIdx.x;

    const unsigned* eg = (const unsigned*)ea2 + ((size_t)b * Hn * NEn) * (Ln / 2) + c * (CL / 2);
    for (int id = t; id < Hn * NEn * 16; id += 256) {
        const int r = id >> 4, u = id & 15;
        sm[r * 17 + u] = eg[(size_t)r * (Ln / 2) + u];
    }
    __syncthreads();

    const int l2 = t & 15;       // uint index within chunk (2 l's each)
    const int pm = t >> 4;       // 0..15
    const int rend = (half + 1) * HALFP;
    unsigned* xbu = (unsigned*)xb;
    for (int rk = half * HALFP + pm; rk < rend; rk += 16) {
        const int i  = rk / (NEn - 1);
        const int jj = rk % (NEn - 1);
        const int j  = jj + (jj >= i ? 1 : 0);
        float a0 = 0.f, a1 = 0.f;
        #pragma unroll
        for (int h = 0; h < Hn; ++h) {
            const unsigned ui = sm[(h * NEn + i) * 17 + l2];
            const unsigned uj = sm[(h * NEn + j) * 17 + l2];
            const float xi0 = __uint_as_float(ui << 16);
            const float xi1 = __uint_as_float(ui & 0xffff0000u);
            const float xj0 = __uint_as_float(uj << 16);
            const float xj1 = __uint_as_float(uj & 0xffff0000u);
            a0 = fmaf(xi0, xj0, a0);
            a1 = fmaf(xi1, xj1, a1);
        }
        xbu[((size_t)b * Pn + rk) * (Ln / 2) + c * (CL / 2) + l2] =
            (unsigned)f2bf(a0) | ((unsigned)f2bf(a1) << 16);
        float part = a0 + a1;
        part += __shfl_down(part, 8, 16);
        part += __shfl_down(part, 4, 16);
        part += __shfl_down(part, 2, 16);
        part += __shfl_down(part, 1, 16);
        if (l2 == 0)
            Spart[((size_t)b * CHUNKS + c) * Pn + rk] = part;
    }
}

// ---------------------------------------------------------------------------
// K4: bf16 MFMA GEMM. 128x128 tile, BK=32, 4 waves (2x2), 4x4 16x16x32 MFMA.
// NEW: global_load_lds width-16 staging into LINEAR double-buffered LDS
// (m97/m151 pattern), XOR swizzle (chunk ^= (row>>1)&3) applied on BOTH the
// global source address and the ds_read offset (rule #21: both-sides-or-
// neither). One barrier per K-iteration. XCD-contiguous block swizzle (T1,
// 336 % 8 == 0 -> bijective).
// ---------------------------------------------------------------------------
__global__ __launch_bounds__(256) void k_gemm_mfma(
    const unsigned short* __restrict__ xb, const unsigned short* __restrict__ soT,
    const float* __restrict__ Spart, float* __restrict__ out2)
{
    __shared__ __align__(16) unsigned short As[2][128 * 32];
    __shared__ __align__(16) unsigned short Bs[2][128 * 32];
    __shared__ float s_scale[128];

    constexpr int nbx = (Pn + 127) / 128;   // 14
    constexpr int nby = Dn / 128;           // 6
    constexpr int nwg = nbx * nby * Bn;     // 336 (== 8 * 42)
    int bid = (int)blockIdx.x;
    bid = (bid & 7) * (nwg >> 3) + (bid >> 3);   // XCD-aware swizzle
    const int b    = bid / (nbx * nby);
    const int rem  = bid % (nbx * nby);
    const int row0 = (rem % nbx) * 128;
    const int col0 = (rem / nbx) * 128;

    const int t    = threadIdx.x;
    const int lane = t & 63;
    const int wave = t >> 6;
    const int wm = wave & 1, wn = wave >> 1;

    // fused k_sreduce: per-row normalizer (visible to epilogue via loop barriers)
    if (t < 128) {
        const int r = min(row0 + t, Pn - 1);
        float s = 0.f;
        #pragma unroll
        for (int cix = 0; cix < CHUNKS; ++cix)
            s += Spart[((size_t)b * CHUNKS + cix) * Pn + r];
        s_scale[t] = 1.0f / (s + (float)Hn * EPSn);
    }

    f32x4 acc[4][4];
    #pragma unroll
    for (int i2 = 0; i2 < 4; ++i2)
        #pragma unroll
        for (int j2 = 0; j2 < 4; ++j2)
            acc[i2][j2] = (f32x4){0.f, 0.f, 0.f, 0.f};

    // Staging: each thread owns 16B chunk q=t (rows 0..63) and q=t+256
    // (rows 64..127) of both A and B tiles. Chunk (row, c16) in LDS holds
    // global k-chunk (c16 ^ ((row>>1)&3)) -- swizzle carried by the global
    // source address since global_load_lds writes LDS linearly.
    const int rqa = t >> 2;            // 0..63
    const int rqb = rqa + 64;
    const int cq  = t & 3;
    const int sca = (cq ^ ((rqa >> 1) & 3)) * 8;   // element offset in row
    const int scb = (cq ^ ((rqb >> 1) & 3)) * 8;
    const unsigned short* gA0 = xb  + ((size_t)b * Pn + min(row0 + rqa, Pn - 1)) * Ln + sca;
    const unsigned short* gA1 = xb  + ((size_t)b * Pn + min(row0 + rqb, Pn - 1)) * Ln + scb;
    const unsigned short* gB0 = soT + ((size_t)b * Dn + col0 + rqa) * Ln + sca;
    const unsigned short* gB1 = soT + ((size_t)b * Dn + col0 + rqb) * Ln + scb;
    const int ldsOff0 = (wave << 6) * 8;           // wave-uniform LDS base (shorts)
    const int ldsOff1 = ldsOff0 + 256 * 8;

    // fragment ds_read offsets (same XOR on the read side)
    const int fr   = lane & 15;                    // fragment row
    const int koq  = lane >> 4;                    // logical k-chunk 0..3
    const int coff = (koq ^ ((fr >> 1) & 3)) * 8;  // swizzled chunk offset

    // prologue: tile 0 -> LDS buf 0
    gld16(gA0, &As[0][ldsOff0]);
    gld16(gA1, &As[0][ldsOff1]);
    gld16(gB0, &Bs[0][ldsOff0]);
    gld16(gB1, &Bs[0][ldsOff1]);
    __syncthreads();

    for (int k0 = 0; k0 < 32; ++k0) {
        const int cur = k0 & 1;
        if (k0 < 31) {
            // async prefetch next K-tile into the other buffer; it was last
            // read in iter k0-1 which ended with a barrier -> safe to fill.
            const int koff = (k0 + 1) * 32;
            const int nxt = cur ^ 1;
            gld16(gA0 + koff, &As[nxt][ldsOff0]);
            gld16(gA1 + koff, &As[nxt][ldsOff1]);
            gld16(gB0 + koff, &Bs[nxt][ldsOff0]);
            gld16(gB1 + koff, &Bs[nxt][ldsOff1]);
        }

        bf16x8 af[4], bfr[4];
        #pragma unroll
        for (int mt = 0; mt < 4; ++mt)
            af[mt] = *(const bf16x8*)&As[cur][(wm * 64 + mt * 16 + fr) * 32 + coff];
        #pragma unroll
        for (int nt = 0; nt < 4; ++nt)
            bfr[nt] = *(const bf16x8*)&Bs[cur][(wn * 64 + nt * 16 + fr) * 32 + coff];
        #pragma unroll
        for (int mt = 0; mt < 4; ++mt)
            #pragma unroll
            for (int nt = 0; nt < 4; ++nt)
                acc[mt][nt] = __builtin_amdgcn_mfma_f32_16x16x32_bf16(
                    af[mt], bfr[nt], acc[mt][nt], 0, 0, 0);

        // barrier drains vmcnt (prefetched tile landed) + orders LDS reuse
        __syncthreads();
    }

    const int ccol  = lane & 15;
    const int crow4 = (lane >> 4) * 4;
    #pragma unroll
    for (int mt = 0; mt < 4; ++mt) {
        #pragma unroll
        for (int rg = 0; rg < 4; ++rg) {
            const int ml = wm * 64 + mt * 16 + crow4 + rg;
            const int r  = row0 + ml;
            if (r < Pn) {
                const float sc2 = s_scale[ml];
                float* dst = out2 + ((size_t)b * Pn + r) * Dn + col0 + wn * 64 + ccol;
                #pragma unroll
                for (int nt = 0; nt < 4; ++nt)
                    dst[nt * 16] = acc[mt][nt][rg] * sc2;
            }
        }
    }
}

extern "C" void kernel_launch(void* const* d_in, const int* in_sizes, int n_in,
                              void* d_out, int out_size, void* d_ws, size_t ws_size,
                              hipStream_t stream)
{
    const float* so   = (const float*)d_in[0];   // (B, L, D)
    const float* att  = (const float*)d_in[1];   // (B, H, L, L)
    const float* mask = (const float*)d_in[2];   // (B, NE, M)
    const int*   mpos = (const int*)d_in[3];     // (B, NE, M)
    float* out = (float*)d_out;
    float* out_ee = out;                                  // B*NE*D
    float* out_ht = out + (size_t)Bn * NEn * Dn;          // B*P*D

    char* w = (char*)d_ws;
    unsigned short* ea2 = (unsigned short*)w; w += (size_t)Bn * Hn * NEn * Ln * 2;  // 4.13 MB
    unsigned short* xb  = (unsigned short*)w; w += (size_t)Bn * Pn * Ln * 2;        // 14.11 MB
    unsigned short* soT = (unsigned short*)w; w += (size_t)Bn * Dn * Ln * 2;        // 6.29 MB
    float* Spart = (float*)w;                                                       // 0.88 MB

    hipLaunchKernelGGL(k_prep, dim3(SOT_BLKS + EA_BLKS), dim3(256), 0, stream,
                       so, att, mask, mpos, soT, ea2);
    hipLaunchKernelGGL(k_pairs, dim3(CHUNKS, 2, Bn), dim3(256), 0, stream,
                       ea2, xb, Spart);
    hipLaunchKernelGGL(k_gemm_mfma, dim3((Pn + 127) / 128 * (Dn / 128) * Bn), dim3(256), 0, stream,
                       xb, soT, Spart, out_ht);
    // entity_embed last: output-0 region written by exactly one kernel, at the end
    hipLaunchKernelGGL(k_entity_embed, dim3(Bn * NEn), dim3(256), 0, stream,
                       so, mask, mpos, out_ee);
}

// Round 2
// 305.171 us; speedup vs baseline: 1.0402x; 1.0332x over previous
//
#include <hip/hip_runtime.h>
#include <hip/hip_bf16.h>
#include <math.h>

// Problem constants
constexpr int Bn  = 4;
constexpr int Ln  = 1024;
constexpr int Dn  = 768;
constexpr int Hn  = 12;
constexpr int NEn = 42;
constexpr int Mn  = 8;
constexpr int Pn  = NEn * (NEn - 1);   // 1722
constexpr int OFFn = 1;
constexpr float EPSn = 1e-5f;
constexpr int CL = 32;                 // l-chunk for k_pairs
constexpr int CHUNKS = Ln / CL;        // 32
constexpr int QP = 432;                // quarter of P, rounded up (4*432 >= 1722)

constexpr int SOT_BLKS = (Ln / 64) * (Dn / 32) * Bn;   // 1536
constexpr int EA_BLKS  = Bn * Hn * NEn;                // 2016

typedef __attribute__((ext_vector_type(8))) short bf16x8;
typedef __attribute__((ext_vector_type(4))) float f32x4;

__device__ inline unsigned short f2bf(float v) {  // RNE fp32 -> bf16 bits
    unsigned u = __float_as_uint(v);
    u += 0x7fffu + ((u >> 16) & 1u);
    return (unsigned short)(u >> 16);
}

// async global->LDS 16B DMA. LDS dest is wave-uniform base + lane*16 (HW rule),
// so the per-lane GLOBAL address carries any swizzle (guide rule #21).
__device__ inline void gld16(const unsigned short* g, unsigned short* l) {
    typedef __attribute__((address_space(3))) unsigned lds_u32;
    typedef const __attribute__((address_space(1))) unsigned glb_u32;
    __builtin_amdgcn_global_load_lds((glb_u32*)g, (lds_u32*)(uintptr_t)l, 16, 0, 0);
}

// ---------------------------------------------------------------------------
// K1: entity_embed (fp32). Launched LAST (round-4 passing configuration).
// ---------------------------------------------------------------------------
__global__ __launch_bounds__(256) void k_entity_embed(
    const float* __restrict__ so, const float* __restrict__ mask,
    const int* __restrict__ mpos, float* __restrict__ out)
{
    const int be = blockIdx.x;
    const int b = be / NEn, e = be % NEn;
    __shared__ int   s_idx[Mn];
    __shared__ float s_msk[Mn];
    if (threadIdx.x < Mn) {
        const int m = threadIdx.x;
        s_idx[m] = mpos[(b * NEn + e) * Mn + m] + OFFn;
        s_msk[m] = mask[(b * NEn + e) * Mn + m];
    }
    __syncthreads();
    for (int d = threadIdx.x; d < Dn; d += 256) {
        float v[Mn];
        float mx = -3.4e38f;
        #pragma unroll
        for (int m = 0; m < Mn; ++m) {
            const float val = so[((size_t)b * Ln + s_idx[m]) * Dn + d];
            v[m] = (s_msk[m] > 0.f) ? val : -3.4e38f;
            mx = fmaxf(mx, v[m]);
        }
        float s = 0.f;
        #pragma unroll
        for (int m = 0; m < Mn; ++m)
            s += (v[m] > -3.0e38f) ? __expf(v[m] - mx) : 0.f;
        out[((size_t)b * NEn + e) * Dn + d] = mx + __logf(s);
    }
}

// ---------------------------------------------------------------------------
// K_prep: fused  [blocks 0..SOT_BLKS)  : so -> soT (bf16, transposed)
//                [SOT_BLKS..+EA_BLKS)  : entity_att -> ea2 (bf16)
// Transpose now uses 64(l) x 32(d) tiles with paired-ushort stores
// (4 B/lane, 128 B contiguous per d-row) instead of 2 B/lane.
// ---------------------------------------------------------------------------
__global__ __launch_bounds__(256) void k_prep(
    const float* __restrict__ so, const float* __restrict__ att,
    const float* __restrict__ mask, const int* __restrict__ mpos,
    unsigned short* __restrict__ soT, unsigned short* __restrict__ ea2)
{
    const int bx = blockIdx.x;
    if (bx < SOT_BLKS) {
        __shared__ unsigned short tile[64][33];   // [l_local][d_local]
        constexpr int tilesPerB = (Ln / 64) * (Dn / 32);   // 384
        const int rem = bx % tilesPerB;
        const int b   = bx / tilesPerB;
        const int l0  = (rem % (Ln / 64)) * 64;
        const int d0  = (rem / (Ln / 64)) * 32;
        const int cx = threadIdx.x & 31;
        const int ry = threadIdx.x >> 5;  // 0..7
        for (int r = ry; r < 64; r += 8)
            tile[r][cx] = f2bf(so[((size_t)b * Ln + l0 + r) * Dn + d0 + cx]);
        __syncthreads();
        // store: each d-row is 64 l's = 32 uints, written by 32 lanes (128 B)
        for (int r = ry; r < 32; r += 8) {
            const unsigned v = (unsigned)tile[2 * cx][r] |
                               ((unsigned)tile[2 * cx + 1][r] << 16);
            *(unsigned*)&soT[((size_t)b * Dn + d0 + r) * Ln + l0 + 2 * cx] = v;
        }
    } else {
        const int id = bx - SOT_BLKS;     // ((b*H)+h)*NE + e
        const int e = id % NEn;
        const int bh = id / NEn;
        const int h = bh % Hn;
        const int b = bh / Hn;
        __shared__ int   s_idx[Mn];
        __shared__ float s_w[Mn];
        __shared__ float s_inv;
        if (threadIdx.x == 0) {
            float sum = 0.f;
            for (int m = 0; m < Mn; ++m) {
                s_idx[m] = mpos[(b * NEn + e) * Mn + m] + OFFn;
                const float w = mask[(b * NEn + e) * Mn + m];
                s_w[m] = w; sum += w;
            }
            s_inv = 1.f / sum;
        }
        __syncthreads();
        const int l = threadIdx.x * 4;
        float4 acc = {0.f, 0.f, 0.f, 0.f};
        #pragma unroll
        for (int m = 0; m < Mn; ++m) {
            if (s_w[m] > 0.f) {
                const float4 v = *(const float4*)&att[(((size_t)b * Hn + h) * Ln + s_idx[m]) * Ln + l];
                acc.x += v.x; acc.y += v.y; acc.z += v.z; acc.w += v.w;
            }
        }
        const unsigned u0 = (unsigned)f2bf(acc.x * s_inv) | ((unsigned)f2bf(acc.y * s_inv) << 16);
        const unsigned u1 = (unsigned)f2bf(acc.z * s_inv) | ((unsigned)f2bf(acc.w * s_inv) << 16);
        uint2 uu; uu.x = u0; uu.y = u1;
        *(uint2*)&ea2[((size_t)id) * Ln + l] = uu;
    }
}

// ---------------------------------------------------------------------------
// K3a: pair scores, unnormalized, PAIR-RANK order.
// NOW: quarters of P (grid 512 blocks, 2 blocks/CU) for latency hiding.
// ---------------------------------------------------------------------------
__global__ __launch_bounds__(256) void k_pairs(
    const unsigned short* __restrict__ ea2, unsigned short* __restrict__ xb,
    float* __restrict__ Spart)
{
    __shared__ unsigned sm[Hn * NEn * 17];   // [h*NE+e][16 uints + 1 pad]
    const int c    = blockIdx.x;
    const int q    = blockIdx.y;             // quarter 0..3
    const int b    = blockIdx.z;
    const int t    = threadIdx.x;

    const unsigned* eg = (const unsigned*)ea2 + ((size_t)b * Hn * NEn) * (Ln / 2) + c * (CL / 2);
    for (int id = t; id < Hn * NEn * 16; id += 256) {
        const int r = id >> 4, u = id & 15;
        sm[r * 17 + u] = eg[(size_t)r * (Ln / 2) + u];
    }
    __syncthreads();

    const int l2 = t & 15;       // uint index within chunk (2 l's each)
    const int pm = t >> 4;       // 0..15
    const int rend = min((q + 1) * QP, Pn);
    unsigned* xbu = (unsigned*)xb;
    for (int rk = q * QP + pm; rk < rend; rk += 16) {
        const int i  = rk / (NEn - 1);
        const int jj = rk % (NEn - 1);
        const int j  = jj + (jj >= i ? 1 : 0);
        float a0 = 0.f, a1 = 0.f;
        #pragma unroll
        for (int h = 0; h < Hn; ++h) {
            const unsigned ui = sm[(h * NEn + i) * 17 + l2];
            const unsigned uj = sm[(h * NEn + j) * 17 + l2];
            const float xi0 = __uint_as_float(ui << 16);
            const float xi1 = __uint_as_float(ui & 0xffff0000u);
            const float xj0 = __uint_as_float(uj << 16);
            const float xj1 = __uint_as_float(uj & 0xffff0000u);
            a0 = fmaf(xi0, xj0, a0);
            a1 = fmaf(xi1, xj1, a1);
        }
        xbu[((size_t)b * Pn + rk) * (Ln / 2) + c * (CL / 2) + l2] =
            (unsigned)f2bf(a0) | ((unsigned)f2bf(a1) << 16);
        float part = a0 + a1;
        part += __shfl_down(part, 8, 16);
        part += __shfl_down(part, 4, 16);
        part += __shfl_down(part, 2, 16);
        part += __shfl_down(part, 1, 16);
        if (l2 == 0)
            Spart[((size_t)b * CHUNKS + c) * Pn + rk] = part;
    }
}

// ---------------------------------------------------------------------------
// K4: bf16 MFMA GEMM. NOW 64x128 tile (was 128x128): grid 336 -> 648 blocks
// (~2.5 blocks/CU, 2-3 waves/SIMD TLP to hide prefetch latency), BK=32,
// 4 waves (2 row x 2 col), each wave 32x64 via 2x4 16x16x32 MFMA.
// global_load_lds width-16 staging, both-sides XOR swizzle (rule #21),
// one barrier per K-iteration, bijective XCD swizzle (648 = 8*81).
// ---------------------------------------------------------------------------
__global__ __launch_bounds__(256) void k_gemm_mfma(
    const unsigned short* __restrict__ xb, const unsigned short* __restrict__ soT,
    const float* __restrict__ Spart, float* __restrict__ out2)
{
    __shared__ __align__(16) unsigned short As[2][64 * 32];
    __shared__ __align__(16) unsigned short Bs[2][128 * 32];
    __shared__ float s_scale[64];

    constexpr int nbx = (Pn + 63) / 64;     // 27
    constexpr int nby = Dn / 128;           // 6
    constexpr int nwg = nbx * nby * Bn;     // 648 (== 8 * 81)
    int bid = (int)blockIdx.x;
    bid = (bid & 7) * (nwg >> 3) + (bid >> 3);   // XCD-aware swizzle (bijective)
    const int b    = bid / (nbx * nby);
    const int rem  = bid % (nbx * nby);
    const int row0 = (rem % nbx) * 64;
    const int col0 = (rem / nbx) * 128;

    const int t    = threadIdx.x;
    const int lane = t & 63;
    const int wave = t >> 6;
    const int wm = wave & 1, wn = wave >> 1;

    // fused k_sreduce: per-row normalizer (visible to epilogue via loop barriers)
    if (t < 64) {
        const int r = min(row0 + t, Pn - 1);
        float s = 0.f;
        #pragma unroll
        for (int cix = 0; cix < CHUNKS; ++cix)
            s += Spart[((size_t)b * CHUNKS + cix) * Pn + r];
        s_scale[t] = 1.0f / (s + (float)Hn * EPSn);
    }

    f32x4 acc[2][4];
    #pragma unroll
    for (int i2 = 0; i2 < 2; ++i2)
        #pragma unroll
        for (int j2 = 0; j2 < 4; ++j2)
            acc[i2][j2] = (f32x4){0.f, 0.f, 0.f, 0.f};

    // Staging: A tile 64x32 = 256 x 16B chunks (one per thread);
    // B tile 128x32 = 512 chunks (two per thread). Chunk (row, c16) in LDS
    // holds global k-chunk (c16 ^ ((row>>1)&3)) -- swizzle carried by the
    // global source address since global_load_lds writes LDS linearly.
    const int rq = t >> 2;             // 0..63
    const int cq = t & 3;
    const int sw0 = (cq ^ ((rq >> 1) & 3)) * 8;           // rows 0..63 key
    const int sw1 = (cq ^ (((rq + 64) >> 1) & 3)) * 8;    // rows 64..127 key
    const unsigned short* gA  = xb  + ((size_t)b * Pn + min(row0 + rq, Pn - 1)) * Ln + sw0;
    const unsigned short* gB0 = soT + ((size_t)b * Dn + col0 + rq) * Ln + sw0;
    const unsigned short* gB1 = soT + ((size_t)b * Dn + col0 + rq + 64) * Ln + sw1;
    const int ldsOffA  = (wave << 6) * 8;          // wave-uniform LDS base (shorts)
    const int ldsOffB0 = (wave << 6) * 8;
    const int ldsOffB1 = 2048 + (wave << 6) * 8;

    // fragment ds_read offsets (same XOR on the read side)
    const int fr   = lane & 15;                    // fragment row
    const int koq  = lane >> 4;                    // logical k-chunk 0..3
    const int coff = (koq ^ ((fr >> 1) & 3)) * 8;  // swizzled chunk offset

    // prologue: tile 0 -> LDS buf 0
    gld16(gA,  &As[0][ldsOffA]);
    gld16(gB0, &Bs[0][ldsOffB0]);
    gld16(gB1, &Bs[0][ldsOffB1]);
    __syncthreads();

    for (int k0 = 0; k0 < 32; ++k0) {
        const int cur = k0 & 1;
        if (k0 < 31) {
            // async prefetch next K-tile into the other buffer; it was last
            // read in iter k0-1 which ended with a barrier -> safe to fill.
            const int koff = (k0 + 1) * 32;
            const int nxt = cur ^ 1;
            gld16(gA  + koff, &As[nxt][ldsOffA]);
            gld16(gB0 + koff, &Bs[nxt][ldsOffB0]);
            gld16(gB1 + koff, &Bs[nxt][ldsOffB1]);
        }

        bf16x8 af[2], bfr[4];
        #pragma unroll
        for (int mt = 0; mt < 2; ++mt)
            af[mt] = *(const bf16x8*)&As[cur][(wm * 32 + mt * 16 + fr) * 32 + coff];
        #pragma unroll
        for (int nt = 0; nt < 4; ++nt)
            bfr[nt] = *(const bf16x8*)&Bs[cur][(wn * 64 + nt * 16 + fr) * 32 + coff];
        #pragma unroll
        for (int mt = 0; mt < 2; ++mt)
            #pragma unroll
            for (int nt = 0; nt < 4; ++nt)
                acc[mt][nt] = __builtin_amdgcn_mfma_f32_16x16x32_bf16(
                    af[mt], bfr[nt], acc[mt][nt], 0, 0, 0);

        // barrier drains vmcnt (prefetched tile landed) + orders LDS reuse
        __syncthreads();
    }

    const int ccol  = lane & 15;
    const int crow4 = (lane >> 4) * 4;
    #pragma unroll
    for (int mt = 0; mt < 2; ++mt) {
        #pragma unroll
        for (int rg = 0; rg < 4; ++rg) {
            const int ml = wm * 32 + mt * 16 + crow4 + rg;
            const int r  = row0 + ml;
            if (r < Pn) {
                const float sc2 = s_scale[ml];
                float* dst = out2 + ((size_t)b * Pn + r) * Dn + col0 + wn * 64 + ccol;
                #pragma unroll
                for (int nt = 0; nt < 4; ++nt)
                    dst[nt * 16] = acc[mt][nt][rg] * sc2;
            }
        }
    }
}

extern "C" void kernel_launch(void* const* d_in, const int* in_sizes, int n_in,
                              void* d_out, int out_size, void* d_ws, size_t ws_size,
                              hipStream_t stream)
{
    const float* so   = (const float*)d_in[0];   // (B, L, D)
    const float* att  = (const float*)d_in[1];   // (B, H, L, L)
    const float* mask = (const float*)d_in[2];   // (B, NE, M)
    const int*   mpos = (const int*)d_in[3];     // (B, NE, M)
    float* out = (float*)d_out;
    float* out_ee = out;                                  // B*NE*D
    float* out_ht = out + (size_t)Bn * NEn * Dn;          // B*P*D

    char* w = (char*)d_ws;
    unsigned short* ea2 = (unsigned short*)w; w += (size_t)Bn * Hn * NEn * Ln * 2;  // 4.13 MB
    unsigned short* xb  = (unsigned short*)w; w += (size_t)Bn * Pn * Ln * 2;        // 14.11 MB
    unsigned short* soT = (unsigned short*)w; w += (size_t)Bn * Dn * Ln * 2;        // 6.29 MB
    float* Spart = (float*)w;                                                       // 0.88 MB

    hipLaunchKernelGGL(k_prep, dim3(SOT_BLKS + EA_BLKS), dim3(256), 0, stream,
                       so, att, mask, mpos, soT, ea2);
    hipLaunchKernelGGL(k_pairs, dim3(CHUNKS, 4, Bn), dim3(256), 0, stream,
                       ea2, xb, Spart);
    hipLaunchKernelGGL(k_gemm_mfma, dim3(((Pn + 63) / 64) * (Dn / 128) * Bn), dim3(256), 0, stream,
                       xb, soT, Spart, out_ht);
    // entity_embed last: output-0 region written by exactly one kernel, at the end
    hipLaunchKernelGGL(k_entity_embed, dim3(Bn * NEn), dim3(256), 0, stream,
                       so, mask, mpos, out_ee);
}

// Round 3
// 302.085 us; speedup vs baseline: 1.0508x; 1.0102x over previous
//
#include <hip/hip_runtime.h>
#include <hip/hip_bf16.h>
#include <math.h>

// Problem constants
constexpr int Bn  = 4;
constexpr int Ln  = 1024;
constexpr int Dn  = 768;
constexpr int Hn  = 12;
constexpr int NEn = 42;
constexpr int Mn  = 8;
constexpr int Pn  = NEn * (NEn - 1);   // 1722
constexpr int OFFn = 1;
constexpr float EPSn = 1e-5f;
constexpr int CL = 32;                 // l-chunk for k_pairs
constexpr int CHUNKS = Ln / CL;        // 32

constexpr int SOT_BLKS = (Ln / 64) * (Dn / 32) * Bn;   // 1536
constexpr int EA_BLKS  = Bn * Hn * NEn;                // 2016

typedef __attribute__((ext_vector_type(8))) short bf16x8;
typedef __attribute__((ext_vector_type(4))) float f32x4;
typedef __attribute__((ext_vector_type(16))) float f32x16;

__device__ inline unsigned short f2bf(float v) {  // RNE fp32 -> bf16 bits
    unsigned u = __float_as_uint(v);
    u += 0x7fffu + ((u >> 16) & 1u);
    return (unsigned short)(u >> 16);
}

// async global->LDS 16B DMA. LDS dest is wave-uniform base + lane*16 (HW rule),
// so the per-lane GLOBAL address carries any swizzle (guide rule #21).
__device__ inline void gld16(const unsigned short* g, unsigned short* l) {
    typedef __attribute__((address_space(3))) unsigned lds_u32;
    typedef const __attribute__((address_space(1))) unsigned glb_u32;
    __builtin_amdgcn_global_load_lds((glb_u32*)g, (lds_u32*)(uintptr_t)l, 16, 0, 0);
}

// ---------------------------------------------------------------------------
// K1: entity_embed (fp32). Launched LAST (passing configuration).
// NOW: 192 threads, one float4 per thread (16 B/lane gathers, one pass).
// ---------------------------------------------------------------------------
__global__ __launch_bounds__(192) void k_entity_embed(
    const float* __restrict__ so, const float* __restrict__ mask,
    const int* __restrict__ mpos, float* __restrict__ out)
{
    const int be = blockIdx.x;
    const int b = be / NEn, e = be % NEn;
    __shared__ int   s_idx[Mn];
    __shared__ float s_msk[Mn];
    if (threadIdx.x < Mn) {
        const int m = threadIdx.x;
        s_idx[m] = mpos[(b * NEn + e) * Mn + m] + OFFn;
        s_msk[m] = mask[(b * NEn + e) * Mn + m];
    }
    __syncthreads();
    const int t = threadIdx.x;           // 0..191, covers Dn/4 float4 slots
    float v[4][Mn];                      // [component][mention]
    #pragma unroll
    for (int m = 0; m < Mn; ++m) {
        if (s_msk[m] > 0.f) {            // wave-uniform branch
            const float4 t4 = *(const float4*)&so[((size_t)b * Ln + s_idx[m]) * Dn + 4 * t];
            v[0][m] = t4.x; v[1][m] = t4.y; v[2][m] = t4.z; v[3][m] = t4.w;
        } else {
            v[0][m] = v[1][m] = v[2][m] = v[3][m] = -3.4e38f;
        }
    }
    float4 res;
    float* rp = (float*)&res;
    #pragma unroll
    for (int c = 0; c < 4; ++c) {
        float mx = -3.4e38f;
        #pragma unroll
        for (int m = 0; m < Mn; ++m) mx = fmaxf(mx, v[c][m]);
        float s = 0.f;
        #pragma unroll
        for (int m = 0; m < Mn; ++m)
            s += (v[c][m] > -3.0e38f) ? __expf(v[c][m] - mx) : 0.f;
        rp[c] = mx + __logf(s);
    }
    *(float4*)&out[((size_t)b * NEn + e) * Dn + 4 * t] = res;
}

// ---------------------------------------------------------------------------
// K_prep: fused  [blocks 0..SOT_BLKS)  : so -> soT (bf16, transposed)
//                [SOT_BLKS..+EA_BLKS)  : entity_att -> ea2 (bf16)
// ---------------------------------------------------------------------------
__global__ __launch_bounds__(256) void k_prep(
    const float* __restrict__ so, const float* __restrict__ att,
    const float* __restrict__ mask, const int* __restrict__ mpos,
    unsigned short* __restrict__ soT, unsigned short* __restrict__ ea2)
{
    const int bx = blockIdx.x;
    if (bx < SOT_BLKS) {
        __shared__ unsigned short tile[64][33];   // [l_local][d_local]
        constexpr int tilesPerB = (Ln / 64) * (Dn / 32);   // 384
        const int rem = bx % tilesPerB;
        const int b   = bx / tilesPerB;
        const int l0  = (rem % (Ln / 64)) * 64;
        const int d0  = (rem / (Ln / 64)) * 32;
        const int cx = threadIdx.x & 31;
        const int ry = threadIdx.x >> 5;  // 0..7
        for (int r = ry; r < 64; r += 8)
            tile[r][cx] = f2bf(so[((size_t)b * Ln + l0 + r) * Dn + d0 + cx]);
        __syncthreads();
        // store: each d-row is 64 l's = 32 uints, written by 32 lanes (128 B)
        for (int r = ry; r < 32; r += 8) {
            const unsigned v = (unsigned)tile[2 * cx][r] |
                               ((unsigned)tile[2 * cx + 1][r] << 16);
            *(unsigned*)&soT[((size_t)b * Dn + d0 + r) * Ln + l0 + 2 * cx] = v;
        }
    } else {
        const int id = bx - SOT_BLKS;     // ((b*H)+h)*NE + e
        const int e = id % NEn;
        const int bh = id / NEn;
        const int h = bh % Hn;
        const int b = bh / Hn;
        __shared__ int   s_idx[Mn];
        __shared__ float s_w[Mn];
        __shared__ float s_inv;
        if (threadIdx.x == 0) {
            float sum = 0.f;
            for (int m = 0; m < Mn; ++m) {
                s_idx[m] = mpos[(b * NEn + e) * Mn + m] + OFFn;
                const float w = mask[(b * NEn + e) * Mn + m];
                s_w[m] = w; sum += w;
            }
            s_inv = 1.f / sum;
        }
        __syncthreads();
        const int l = threadIdx.x * 4;
        float4 acc = {0.f, 0.f, 0.f, 0.f};
        #pragma unroll
        for (int m = 0; m < Mn; ++m) {
            if (s_w[m] > 0.f) {
                const float4 v = *(const float4*)&att[(((size_t)b * Hn + h) * Ln + s_idx[m]) * Ln + l];
                acc.x += v.x; acc.y += v.y; acc.z += v.z; acc.w += v.w;
            }
        }
        const unsigned u0 = (unsigned)f2bf(acc.x * s_inv) | ((unsigned)f2bf(acc.y * s_inv) << 16);
        const unsigned u1 = (unsigned)f2bf(acc.z * s_inv) | ((unsigned)f2bf(acc.w * s_inv) << 16);
        uint2 uu; uu.x = u0; uu.y = u1;
        *(uint2*)&ea2[((size_t)id) * Ln + l] = uu;
    }
}

// ---------------------------------------------------------------------------
// K3a: pair scores, unnormalized, PAIR-RANK order.
// NOW: i-outer loop with the i-entity row (12 heads) cached in REGISTERS
// (unpacked once), inner loop over j reads only the j-row from LDS:
// 12 b32 reads + half the unpack per pair (was 24 + full unpack).
// Grid (CHUNKS, 6 i-groups, B) = 768 blocks (3/CU).
// ---------------------------------------------------------------------------
__global__ __launch_bounds__(256) void k_pairs(
    const unsigned short* __restrict__ ea2, unsigned short* __restrict__ xb,
    float* __restrict__ Spart)
{
    __shared__ unsigned sm[Hn * NEn * 17];   // [h*NE+e][16 uints + 1 pad]
    const int c    = blockIdx.x;
    const int g    = blockIdx.y;             // i-group 0..5 (7 i's each)
    const int b    = blockIdx.z;
    const int t    = threadIdx.x;

    const unsigned* eg = (const unsigned*)ea2 + ((size_t)b * Hn * NEn) * (Ln / 2) + c * (CL / 2);
    for (int id = t; id < Hn * NEn * 16; id += 256) {
        const int r = id >> 4, u = id & 15;
        sm[r * 17 + u] = eg[(size_t)r * (Ln / 2) + u];
    }
    __syncthreads();

    const int l2 = t & 15;       // uint index within chunk (2 l's each)
    const int pm = t >> 4;       // 0..15 (j-slot lane group)
    unsigned* xbu = (unsigned*)xb;

    for (int i = g * 7; i < g * 7 + 7; ++i) {
        // cache entity-i row (all heads) in registers, unpack once
        float xi0[Hn], xi1[Hn];
        #pragma unroll
        for (int h = 0; h < Hn; ++h) {
            const unsigned ui = sm[(h * NEn + i) * 17 + l2];
            xi0[h] = __uint_as_float(ui << 16);
            xi1[h] = __uint_as_float(ui & 0xffff0000u);
        }
        for (int jj = pm; jj < NEn - 1; jj += 16) {
            const int j = jj + (jj >= i ? 1 : 0);
            float a0 = 0.f, a1 = 0.f;
            #pragma unroll
            for (int h = 0; h < Hn; ++h) {
                const unsigned uj = sm[(h * NEn + j) * 17 + l2];
                a0 = fmaf(xi0[h], __uint_as_float(uj << 16), a0);
                a1 = fmaf(xi1[h], __uint_as_float(uj & 0xffff0000u), a1);
            }
            const int rk = i * (NEn - 1) + jj;
            xbu[((size_t)b * Pn + rk) * (Ln / 2) + c * (CL / 2) + l2] =
                (unsigned)f2bf(a0) | ((unsigned)f2bf(a1) << 16);
            float part = a0 + a1;
            part += __shfl_down(part, 8, 16);
            part += __shfl_down(part, 4, 16);
            part += __shfl_down(part, 2, 16);
            part += __shfl_down(part, 1, 16);
            if (l2 == 0)
                Spart[((size_t)b * CHUNKS + c) * Pn + rk] = part;
        }
    }
}

// ---------------------------------------------------------------------------
// K4: bf16 MFMA GEMM, 64x128 tile, BK=32, 4 waves (2x2), wave = 32x64.
// NOW mfma_f32_32x32x16_bf16: 4 MFMA/iter/wave (was 8 of 16x16x32) for the
// same FLOPs -- 2382 vs 2075 TF ubench rate, half the issue slots.
// Staging: global_load_lds w16, both-sides XOR swizzle, 1 barrier/iter,
// bijective XCD swizzle (648 = 8*81). C/D layout (m74/m101):
// col=lane&31, row=(reg&3)+8*(reg>>2)+4*(lane>>5).
// ---------------------------------------------------------------------------
__global__ __launch_bounds__(256) void k_gemm_mfma(
    const unsigned short* __restrict__ xb, const unsigned short* __restrict__ soT,
    const float* __restrict__ Spart, float* __restrict__ out2)
{
    __shared__ __align__(16) unsigned short As[2][64 * 32];
    __shared__ __align__(16) unsigned short Bs[2][128 * 32];
    __shared__ float s_scale[64];

    constexpr int nbx = (Pn + 63) / 64;     // 27
    constexpr int nby = Dn / 128;           // 6
    constexpr int nwg = nbx * nby * Bn;     // 648 (== 8 * 81)
    int bid = (int)blockIdx.x;
    bid = (bid & 7) * (nwg >> 3) + (bid >> 3);   // XCD-aware swizzle (bijective)
    const int b    = bid / (nbx * nby);
    const int rem  = bid % (nbx * nby);
    const int row0 = (rem % nbx) * 64;
    const int col0 = (rem / nbx) * 128;

    const int t    = threadIdx.x;
    const int lane = t & 63;
    const int wave = t >> 6;
    const int wm = wave & 1, wn = wave >> 1;

    // fused k_sreduce: per-row normalizer (visible to epilogue via loop barriers)
    if (t < 64) {
        const int r = min(row0 + t, Pn - 1);
        float s = 0.f;
        #pragma unroll
        for (int cix = 0; cix < CHUNKS; ++cix)
            s += Spart[((size_t)b * CHUNKS + cix) * Pn + r];
        s_scale[t] = 1.0f / (s + (float)Hn * EPSn);
    }

    f32x16 acc[2];
    #pragma unroll
    for (int nt = 0; nt < 2; ++nt)
        #pragma unroll
        for (int rg = 0; rg < 16; ++rg)
            acc[nt][rg] = 0.f;

    // Staging (unchanged from passing round-2 kernel): A 64x32 (256 chunks),
    // B 128x32 (512 chunks). LDS chunk (row, c16) holds global k-chunk
    // (c16 ^ ((row>>1)&3)) -- swizzle carried by the global source address.
    const int rq = t >> 2;             // 0..63
    const int cq = t & 3;
    const int sw0 = (cq ^ ((rq >> 1) & 3)) * 8;           // rows 0..63 key
    const int sw1 = (cq ^ (((rq + 64) >> 1) & 3)) * 8;    // rows 64..127 key
    const unsigned short* gA  = xb  + ((size_t)b * Pn + min(row0 + rq, Pn - 1)) * Ln + sw0;
    const unsigned short* gB0 = soT + ((size_t)b * Dn + col0 + rq) * Ln + sw0;
    const unsigned short* gB1 = soT + ((size_t)b * Dn + col0 + rq + 64) * Ln + sw1;
    const int ldsOffA  = (wave << 6) * 8;          // wave-uniform LDS base (shorts)
    const int ldsOffB0 = (wave << 6) * 8;
    const int ldsOffB1 = 2048 + (wave << 6) * 8;

    // fragment ds_read addressing for 32x32x16: row = lane&31, k-half = lane>>5
    const int lr = lane & 31;
    const int kh = lane >> 5;                      // 0..1
    const int rowA = wm * 32 + lr;                 // A-tile row (0..63)
    const int keyA = (rowA >> 1) & 3;
    const int rowB0 = wn * 64 + lr;                // B rows for nt=0 / nt=1
    const int rowB1 = wn * 64 + 32 + lr;
    const int keyB0 = (rowB0 >> 1) & 3;
    const int keyB1 = (rowB1 >> 1) & 3;

    // prologue: tile 0 -> LDS buf 0
    gld16(gA,  &As[0][ldsOffA]);
    gld16(gB0, &Bs[0][ldsOffB0]);
    gld16(gB1, &Bs[0][ldsOffB1]);
    __syncthreads();

    for (int k0 = 0; k0 < 32; ++k0) {
        const int cur = k0 & 1;
        if (k0 < 31) {
            const int koff = (k0 + 1) * 32;
            const int nxt = cur ^ 1;
            gld16(gA  + koff, &As[nxt][ldsOffA]);
            gld16(gB0 + koff, &Bs[nxt][ldsOffB0]);
            gld16(gB1 + koff, &Bs[nxt][ldsOffB1]);
        }

        bf16x8 af[2], bf0[2], bf1[2];
        #pragma unroll
        for (int s = 0; s < 2; ++s) {
            const int cc = s * 2 + kh;   // logical 16B chunk 0..3
            af[s]  = *(const bf16x8*)&As[cur][rowA  * 32 + ((cc ^ keyA)  * 8)];
            bf0[s] = *(const bf16x8*)&Bs[cur][rowB0 * 32 + ((cc ^ keyB0) * 8)];
            bf1[s] = *(const bf16x8*)&Bs[cur][rowB1 * 32 + ((cc ^ keyB1) * 8)];
        }
        #pragma unroll
        for (int s = 0; s < 2; ++s) {
            acc[0] = __builtin_amdgcn_mfma_f32_32x32x16_bf16(af[s], bf0[s], acc[0], 0, 0, 0);
            acc[1] = __builtin_amdgcn_mfma_f32_32x32x16_bf16(af[s], bf1[s], acc[1], 0, 0, 0);
        }

        // barrier drains vmcnt (prefetched tile landed) + orders LDS reuse
        __syncthreads();
    }

    // epilogue: C/D layout col=lane&31, row=(reg&3)+8*(reg>>2)+4*(lane>>5)
    #pragma unroll
    for (int nt = 0; nt < 2; ++nt) {
        #pragma unroll
        for (int rg = 0; rg < 16; ++rg) {
            const int ml = wm * 32 + (rg & 3) + 8 * (rg >> 2) + 4 * kh;
            const int r  = row0 + ml;
            if (r < Pn) {
                out2[((size_t)b * Pn + r) * Dn + col0 + wn * 64 + nt * 32 + lr] =
                    acc[nt][rg] * s_scale[ml];
            }
        }
    }
}

extern "C" void kernel_launch(void* const* d_in, const int* in_sizes, int n_in,
                              void* d_out, int out_size, void* d_ws, size_t ws_size,
                              hipStream_t stream)
{
    const float* so   = (const float*)d_in[0];   // (B, L, D)
    const float* att  = (const float*)d_in[1];   // (B, H, L, L)
    const float* mask = (const float*)d_in[2];   // (B, NE, M)
    const int*   mpos = (const int*)d_in[3];     // (B, NE, M)
    float* out = (float*)d_out;
    float* out_ee = out;                                  // B*NE*D
    float* out_ht = out + (size_t)Bn * NEn * Dn;          // B*P*D

    char* w = (char*)d_ws;
    unsigned short* ea2 = (unsigned short*)w; w += (size_t)Bn * Hn * NEn * Ln * 2;  // 4.13 MB
    unsigned short* xb  = (unsigned short*)w; w += (size_t)Bn * Pn * Ln * 2;        // 14.11 MB
    unsigned short* soT = (unsigned short*)w; w += (size_t)Bn * Dn * Ln * 2;        // 6.29 MB
    float* Spart = (float*)w;                                                       // 0.88 MB

    hipLaunchKernelGGL(k_prep, dim3(SOT_BLKS + EA_BLKS), dim3(256), 0, stream,
                       so, att, mask, mpos, soT, ea2);
    hipLaunchKernelGGL(k_pairs, dim3(CHUNKS, 6, Bn), dim3(256), 0, stream,
                       ea2, xb, Spart);
    hipLaunchKernelGGL(k_gemm_mfma, dim3(((Pn + 63) / 64) * (Dn / 128) * Bn), dim3(256), 0, stream,
                       xb, soT, Spart, out_ht);
    // entity_embed last: output-0 region written by exactly one kernel, at the end
    hipLaunchKernelGGL(k_entity_embed, dim3(Bn * NEn), dim3(192), 0, stream,
                       so, mask, mpos, out_ee);
}